// Round 1
// baseline (110.133 us; speedup 1.0000x reference)
//
#include <hip/hip_runtime.h>

#define NN 512          // nodes
#define IND 512         // in features
#define NH 8            // heads
#define NF 64           // hidden per head

// ---------------------------------------------------------------------------
// K1: fused NT GEMM (no pre-transpose): C[r][c] = sum_k A[r][k] * B[c][k]
//   z=0: A=Ws, B=X  -> C = Gs_t [o][n]
//   z=1: A=X,  B=Wt -> C = Gt   [n][o]
// Block: 8 r x 128 c, 4 waves = 2 row-groups x 2 k-halves (split-K in block).
// B-tile staged to LDS transposed (Vs[k][c]) in 32-k chunks; global loads are
// issued before the chunk barrier so HBM/L2 latency hides under prior FMAs.
// A rows are wave-uniform -> s_loads through K$ (as before).
// Grid: (4, 64, 2) = 512 blocks = 2/CU.
// ---------------------------------------------------------------------------
__global__ __launch_bounds__(256) void gemm_nt(
    const float* __restrict__ Aa, const float* __restrict__ Ba, float* __restrict__ Ca,
    const float* __restrict__ Ab, const float* __restrict__ Bb, float* __restrict__ Cb)
{
    const float* A = blockIdx.z ? Ab : Aa;
    const float* B = blockIdx.z ? Bb : Ba;
    float*       C = blockIdx.z ? Cb : Ca;

    // pitch 132: bank = (4*k + c) % 32 -> 2-way on both write (c-contig) and
    // float2 read (stride-2 lanes); 2-way is free on gfx950. 528B row = 8B-aligned.
    __shared__ __align__(16) float Vs[2][32][132];
    __shared__ float2 sp[2][4][64];

    const int tid  = threadIdx.x;
    const int wv   = __builtin_amdgcn_readfirstlane(tid >> 6);
    const int lane = tid & 63;
    const int rg = wv & 1, kh = wv >> 1;       // kh == tid>>7
    const int r0 = blockIdx.y * 8 + rg * 4;
    const int c0 = blockIdx.x * 128;

    const float* Sp = A + (size_t)r0 * IND + kh * 256;
    const int ts = tid & 127;                  // staging column within kh-group
    const float* Brow = B + (size_t)(c0 + ts) * IND + kh * 256;

    float2 a0 = {0.f,0.f}, a1 = {0.f,0.f}, a2 = {0.f,0.f}, a3 = {0.f,0.f};

    for (int ch = 0; ch < 8; ++ch) {           // 8 chunks of BK=32 per k-half
        // ---- issue global loads early (latency overlaps prior chunk's FMAs)
        float4 f[8];
        const float4* bp = reinterpret_cast<const float4*>(Brow + ch * 32);
        #pragma unroll
        for (int i = 0; i < 8; ++i) f[i] = bp[i];
        __syncthreads();                       // prior chunk fully consumed
        #pragma unroll
        for (int i = 0; i < 8; ++i) {          // transpose into LDS [k][c]
            Vs[kh][i * 4 + 0][ts] = f[i].x;
            Vs[kh][i * 4 + 1][ts] = f[i].y;
            Vs[kh][i * 4 + 2][ts] = f[i].z;
            Vs[kh][i * 4 + 3][ts] = f[i].w;
        }
        __syncthreads();
        const float* Spc = Sp + ch * 32;
        #pragma unroll 8
        for (int kk = 0; kk < 32; ++kk) {
            float2 v = *reinterpret_cast<const float2*>(&Vs[kh][kk][lane * 2]);
            float s0 = Spc[kk];
            float s1 = Spc[IND + kk];
            float s2 = Spc[2 * IND + kk];
            float s3 = Spc[3 * IND + kk];
            a0.x = fmaf(s0, v.x, a0.x); a0.y = fmaf(s0, v.y, a0.y);
            a1.x = fmaf(s1, v.x, a1.x); a1.y = fmaf(s1, v.y, a1.y);
            a2.x = fmaf(s2, v.x, a2.x); a2.y = fmaf(s2, v.y, a2.y);
            a3.x = fmaf(s3, v.x, a3.x); a3.y = fmaf(s3, v.y, a3.y);
        }
    }

    // ---- split-K reduce + store (kh=1 exchanges via LDS, kh=0 writes C)
    if (kh) {
        sp[rg][0][lane] = a0; sp[rg][1][lane] = a1;
        sp[rg][2][lane] = a2; sp[rg][3][lane] = a3;
    }
    __syncthreads();
    if (!kh) {
        float2 p;
        const int cc = c0 + lane * 2;
        p = sp[rg][0][lane]; a0.x += p.x; a0.y += p.y;
        p = sp[rg][1][lane]; a1.x += p.x; a1.y += p.y;
        p = sp[rg][2][lane]; a2.x += p.x; a2.y += p.y;
        p = sp[rg][3][lane]; a3.x += p.x; a3.y += p.y;
        *reinterpret_cast<float2*>(C + (size_t)(r0 + 0) * NN + cc) = a0;
        *reinterpret_cast<float2*>(C + (size_t)(r0 + 1) * NN + cc) = a1;
        *reinterpret_cast<float2*>(C + (size_t)(r0 + 2) * NN + cc) = a2;
        *reinterpret_cast<float2*>(C + (size_t)(r0 + 3) * NN + cc) = a3;
    }
}

// ---------------------------------------------------------------------------
// K2: per (i-tile of 4, head h) block.
//   scores = 0.6*P_j + 0.4*sum_f a_f*|gs_jf + gt_if|   (Q_i dropped: it is
//   constant over j, softmax over j is shift-invariant, and raw scores are
//   never output). P_j accumulated in the same f-loop: 18 VALU/f (was 24).
//   attention written COALESCED to workspace att_ws[h][i][j]; K3 packs to
//   the required [i][j][h] layout (kills the stride-32B scatter and its
//   ~8x cross-XCD partial-line write amplification).
// ---------------------------------------------------------------------------
__global__ __launch_bounds__(256) void gat_attn(
    const float* __restrict__ Gs_t,      // [512 (h*64+f)][512 j]
    const float* __restrict__ Gt,        // [512 n][512 (h*64+f)]
    const float* __restrict__ attn_w,    // [64]
    const int*   __restrict__ adj,       // [512][512]
    float* __restrict__ out_feat,        // [512][512]
    float* __restrict__ att_ws)          // [8 h][512 i][512 j]  (workspace)
{
    __shared__ float s_sc[4][512];
    __shared__ float s_red[4][4][64];

    const int tid = threadIdx.x;
    const int i0  = blockIdx.x * 4;
    const int h   = blockIdx.y;

    // ---- phase 1: scores (2 j's per thread via float2) ----
    {
        const int jj = tid * 2;
        float2 acc0 = {0.f,0.f}, acc1 = {0.f,0.f}, acc2 = {0.f,0.f}, acc3 = {0.f,0.f};
        float2 p = {0.f,0.f};                       // sum_f a_f * gs_jf
        const float* gsp = Gs_t + (size_t)h * NF * NN + jj;
        const float* gtp = Gt + (size_t)i0 * IND + h * NF;
        #pragma unroll 4
        for (int f = 0; f < NF; ++f) {
            float w  = attn_w[f];                   // uniform -> s_load
            float2 g = *reinterpret_cast<const float2*>(gsp + (size_t)f * NN);
            float gt0 = gtp[f];                     // uniform -> s_load
            float gt1 = gtp[IND + f];
            float gt2 = gtp[2 * IND + f];
            float gt3 = gtp[3 * IND + f];
            p.x = fmaf(w, g.x, p.x);
            p.y = fmaf(w, g.y, p.y);
            float tx, ty;
            tx = g.x + gt0; ty = g.y + gt0;
            acc0.x = fmaf(w, fabsf(tx), acc0.x); acc0.y = fmaf(w, fabsf(ty), acc0.y);
            tx = g.x + gt1; ty = g.y + gt1;
            acc1.x = fmaf(w, fabsf(tx), acc1.x); acc1.y = fmaf(w, fabsf(ty), acc1.y);
            tx = g.x + gt2; ty = g.y + gt2;
            acc2.x = fmaf(w, fabsf(tx), acc2.x); acc2.y = fmaf(w, fabsf(ty), acc2.y);
            tx = g.x + gt3; ty = g.y + gt3;
            acc3.x = fmaf(w, fabsf(tx), acc3.x); acc3.y = fmaf(w, fabsf(ty), acc3.y);
        }
        const float px = 0.6f * p.x, py = 0.6f * p.y;
        int2 ad;
        ad = *reinterpret_cast<const int2*>(adj + (size_t)(i0 + 0) * NN + jj);
        s_sc[0][jj]     = ad.x ? fmaf(0.4f, acc0.x, px) : -INFINITY;
        s_sc[0][jj + 1] = ad.y ? fmaf(0.4f, acc0.y, py) : -INFINITY;
        ad = *reinterpret_cast<const int2*>(adj + (size_t)(i0 + 1) * NN + jj);
        s_sc[1][jj]     = ad.x ? fmaf(0.4f, acc1.x, px) : -INFINITY;
        s_sc[1][jj + 1] = ad.y ? fmaf(0.4f, acc1.y, py) : -INFINITY;
        ad = *reinterpret_cast<const int2*>(adj + (size_t)(i0 + 2) * NN + jj);
        s_sc[2][jj]     = ad.x ? fmaf(0.4f, acc2.x, px) : -INFINITY;
        s_sc[2][jj + 1] = ad.y ? fmaf(0.4f, acc2.y, py) : -INFINITY;
        ad = *reinterpret_cast<const int2*>(adj + (size_t)(i0 + 3) * NN + jj);
        s_sc[3][jj]     = ad.x ? fmaf(0.4f, acc3.x, px) : -INFINITY;
        s_sc[3][jj + 1] = ad.y ? fmaf(0.4f, acc3.y, py) : -INFINITY;
    }
    __syncthreads();

    // ---- phase 2: softmax (one wave per row) + coalesced attention write ----
    {
        const int ii = tid >> 6, lane = tid & 63;
        float m = -INFINITY;
        #pragma unroll
        for (int r = 0; r < 8; ++r) m = fmaxf(m, s_sc[ii][lane + r * 64]);
        #pragma unroll
        for (int off = 32; off >= 1; off >>= 1) m = fmaxf(m, __shfl_xor(m, off, 64));
        float e[8];
        float sum = 0.f;
        #pragma unroll
        for (int r = 0; r < 8; ++r) {
            float ev = __expf(s_sc[ii][lane + r * 64] - m);
            e[r] = ev;
            sum += ev;
        }
        #pragma unroll
        for (int off = 32; off >= 1; off >>= 1) sum += __shfl_xor(sum, off, 64);
        float inv = 1.f / sum;
        const int i = i0 + ii;
        float* awp = att_ws + ((size_t)h * NN + i) * NN;
        #pragma unroll
        for (int r = 0; r < 8; ++r) {
            int j = lane + r * 64;
            float a = e[r] * inv;
            s_sc[ii][j] = a;
            awp[j] = a;                       // contiguous per wave-store
        }
    }
    __syncthreads();

    // ---- phase 3: head_output = att @ Gt (waves split j; b128 att broadcast) ----
    {
        const int w = tid >> 6, lane = tid & 63;
        const int jb = w * 128;
        float o0 = 0.f, o1 = 0.f, o2 = 0.f, o3 = 0.f;
        const float* gtc = Gt + h * NF + lane;
        #pragma unroll 4
        for (int s = 0; s < 32; ++s) {
            const int j = jb + 4 * s;
            float4 b0 = *reinterpret_cast<const float4*>(&s_sc[0][j]);
            float4 b1 = *reinterpret_cast<const float4*>(&s_sc[1][j]);
            float4 b2 = *reinterpret_cast<const float4*>(&s_sc[2][j]);
            float4 b3 = *reinterpret_cast<const float4*>(&s_sc[3][j]);
            float gv;
            gv = gtc[(size_t)(j + 0) * IND];
            o0 = fmaf(b0.x, gv, o0); o1 = fmaf(b1.x, gv, o1);
            o2 = fmaf(b2.x, gv, o2); o3 = fmaf(b3.x, gv, o3);
            gv = gtc[(size_t)(j + 1) * IND];
            o0 = fmaf(b0.y, gv, o0); o1 = fmaf(b1.y, gv, o1);
            o2 = fmaf(b2.y, gv, o2); o3 = fmaf(b3.y, gv, o3);
            gv = gtc[(size_t)(j + 2) * IND];
            o0 = fmaf(b0.z, gv, o0); o1 = fmaf(b1.z, gv, o1);
            o2 = fmaf(b2.z, gv, o2); o3 = fmaf(b3.z, gv, o3);
            gv = gtc[(size_t)(j + 3) * IND];
            o0 = fmaf(b0.w, gv, o0); o1 = fmaf(b1.w, gv, o1);
            o2 = fmaf(b2.w, gv, o2); o3 = fmaf(b3.w, gv, o3);
        }
        s_red[w][0][lane] = o0; s_red[w][1][lane] = o1;
        s_red[w][2][lane] = o2; s_red[w][3][lane] = o3;
    }
    __syncthreads();
    {
        const int ii = tid >> 6, f = tid & 63;
        float s = s_red[0][ii][f] + s_red[1][ii][f] + s_red[2][ii][f] + s_red[3][ii][f];
        out_feat[(size_t)(i0 + ii) * (NH * NF) + h * NF + f] = s;
    }
}

// ---------------------------------------------------------------------------
// K3: pack attention  att_ws[h][i][j] -> out_att[i][j][h].
// Reads: 8 coalesced float2 streams; writes: 64 B contiguous per thread,
// 4 KB contiguous per wave. 16 MB total traffic, fully coalesced both sides.
// Grid: 256 blocks (2 i's each) x 256 threads.
// ---------------------------------------------------------------------------
__global__ __launch_bounds__(256) void att_pack(
    const float* __restrict__ att_ws, float* __restrict__ out_att)
{
    const int tid = threadIdx.x;
    const int i0  = blockIdx.x * 2;
    const int jj  = tid * 2;
    #pragma unroll
    for (int ii = 0; ii < 2; ++ii) {
        const int i = i0 + ii;
        float2 v[8];
        #pragma unroll
        for (int h = 0; h < 8; ++h)
            v[h] = *reinterpret_cast<const float2*>(att_ws + ((size_t)h * NN + i) * NN + jj);
        float4* dst = reinterpret_cast<float4*>(out_att + ((size_t)i * NN + jj) * NH);
        float4 o;
        o.x = v[0].x; o.y = v[1].x; o.z = v[2].x; o.w = v[3].x; dst[0] = o;
        o.x = v[4].x; o.y = v[5].x; o.z = v[6].x; o.w = v[7].x; dst[1] = o;
        o.x = v[0].y; o.y = v[1].y; o.z = v[2].y; o.w = v[3].y; dst[2] = o;
        o.x = v[4].y; o.y = v[5].y; o.z = v[6].y; o.w = v[7].y; dst[3] = o;
    }
}

extern "C" void kernel_launch(void* const* d_in, const int* in_sizes, int n_in,
                              void* d_out, int out_size, void* d_ws, size_t ws_size,
                              hipStream_t stream) {
    const float* X   = (const float*)d_in[0];   // h [1,512,512]
    const float* Ws  = (const float*)d_in[1];   // W_source [512,512]
    const float* Wtg = (const float*)d_in[2];   // W_target [512,512]
    const float* aw  = (const float*)d_in[3];   // attn_w [64]
    const int*   adj = (const int*)d_in[4];     // adjacency [512,512,1]

    float* Gs_t   = (float*)d_ws;                    // [512 o][512 n]
    float* Gt     = Gs_t   + (size_t)NN * IND;       // [512 n][512 o]
    float* att_ws = Gt     + (size_t)NN * IND;       // [8][512][512]

    float* out_feat = (float*)d_out;                    // [512,512]
    float* out_att  = out_feat + (size_t)NN * NH * NF;  // [512,512,8]

    // K1: z=0: Gs_t = Ws . X^T ; z=1: Gt = X . Wt^T   (transpose fused via LDS)
    hipLaunchKernelGGL(gemm_nt, dim3(4, 64, 2), dim3(256), 0, stream,
                       Ws, X, Gs_t, X, Wtg, Gt);
    hipLaunchKernelGGL(gat_attn, dim3(NN / 4, NH), dim3(256), 0, stream,
                       Gs_t, Gt, aw, adj, out_feat, att_ws);
    hipLaunchKernelGGL(att_pack, dim3(NN / 2), dim3(256), 0, stream,
                       att_ws, out_att);
}

// Round 2
// 107.192 us; speedup vs baseline: 1.0274x; 1.0274x over previous
//
#include <hip/hip_runtime.h>

#define NN 512          // nodes
#define IND 512         // in features
#define NH 8            // heads
#define NF 64           // hidden per head

// ---------------------------------------------------------------------------
// K1: fused NT GEMM (no pre-transpose): C[r][c] = sum_k A[r][k] * B[c][k]
//   z=0: A=Ws, B=X  -> C = Gs_t [o][n]
//   z=1: A=X,  B=Wt -> C = Gt   [n][o]
// Block: 8 r x 128 c, 4 waves = 2 row-groups x 2 k-halves (split-K in block).
// B-tile staged to LDS transposed (Vs[k][c]) in 32-k chunks; global loads are
// issued before the chunk barrier so HBM/L2 latency hides under prior FMAs.
// A rows are wave-uniform -> s_loads through K$.
// Grid: (4, 64, 2) = 512 blocks = 2/CU.
// ---------------------------------------------------------------------------
__global__ __launch_bounds__(256) void gemm_nt(
    const float* __restrict__ Aa, const float* __restrict__ Ba, float* __restrict__ Ca,
    const float* __restrict__ Ab, const float* __restrict__ Bb, float* __restrict__ Cb)
{
    const float* A = blockIdx.z ? Ab : Aa;
    const float* B = blockIdx.z ? Bb : Ba;
    float*       C = blockIdx.z ? Cb : Ca;

    // pitch 132: bank = (4*k + c) % 32 -> 2-way on both write (c-contig) and
    // float2 read (stride-2 lanes); 2-way is free on gfx950.
    __shared__ __align__(16) float Vs[2][32][132];
    __shared__ float2 sp[2][4][64];

    const int tid  = threadIdx.x;
    const int wv   = __builtin_amdgcn_readfirstlane(tid >> 6);
    const int lane = tid & 63;
    const int rg = wv & 1, kh = wv >> 1;       // kh == tid>>7
    const int r0 = blockIdx.y * 8 + rg * 4;
    const int c0 = blockIdx.x * 128;

    const float* Sp = A + (size_t)r0 * IND + kh * 256;
    const int ts = tid & 127;                  // staging column within kh-group
    const float* Brow = B + (size_t)(c0 + ts) * IND + kh * 256;

    float2 a0 = {0.f,0.f}, a1 = {0.f,0.f}, a2 = {0.f,0.f}, a3 = {0.f,0.f};

    for (int ch = 0; ch < 8; ++ch) {           // 8 chunks of BK=32 per k-half
        // ---- issue global loads early (latency overlaps prior chunk's FMAs)
        float4 f[8];
        const float4* bp = reinterpret_cast<const float4*>(Brow + ch * 32);
        #pragma unroll
        for (int i = 0; i < 8; ++i) f[i] = bp[i];
        __syncthreads();                       // prior chunk fully consumed
        #pragma unroll
        for (int i = 0; i < 8; ++i) {          // transpose into LDS [k][c]
            Vs[kh][i * 4 + 0][ts] = f[i].x;
            Vs[kh][i * 4 + 1][ts] = f[i].y;
            Vs[kh][i * 4 + 2][ts] = f[i].z;
            Vs[kh][i * 4 + 3][ts] = f[i].w;
        }
        __syncthreads();
        const float* Spc = Sp + ch * 32;
        #pragma unroll 8
        for (int kk = 0; kk < 32; ++kk) {
            float2 v = *reinterpret_cast<const float2*>(&Vs[kh][kk][lane * 2]);
            float s0 = Spc[kk];
            float s1 = Spc[IND + kk];
            float s2 = Spc[2 * IND + kk];
            float s3 = Spc[3 * IND + kk];
            a0.x = fmaf(s0, v.x, a0.x); a0.y = fmaf(s0, v.y, a0.y);
            a1.x = fmaf(s1, v.x, a1.x); a1.y = fmaf(s1, v.y, a1.y);
            a2.x = fmaf(s2, v.x, a2.x); a2.y = fmaf(s2, v.y, a2.y);
            a3.x = fmaf(s3, v.x, a3.x); a3.y = fmaf(s3, v.y, a3.y);
        }
    }

    // ---- split-K reduce + store (kh=1 exchanges via LDS, kh=0 writes C)
    if (kh) {
        sp[rg][0][lane] = a0; sp[rg][1][lane] = a1;
        sp[rg][2][lane] = a2; sp[rg][3][lane] = a3;
    }
    __syncthreads();
    if (!kh) {
        float2 p;
        const int cc = c0 + lane * 2;
        p = sp[rg][0][lane]; a0.x += p.x; a0.y += p.y;
        p = sp[rg][1][lane]; a1.x += p.x; a1.y += p.y;
        p = sp[rg][2][lane]; a2.x += p.x; a2.y += p.y;
        p = sp[rg][3][lane]; a3.x += p.x; a3.y += p.y;
        *reinterpret_cast<float2*>(C + (size_t)(r0 + 0) * NN + cc) = a0;
        *reinterpret_cast<float2*>(C + (size_t)(r0 + 1) * NN + cc) = a1;
        *reinterpret_cast<float2*>(C + (size_t)(r0 + 2) * NN + cc) = a2;
        *reinterpret_cast<float2*>(C + (size_t)(r0 + 3) * NN + cc) = a3;
    }
}

// ---------------------------------------------------------------------------
// K2: per (i-tile of 8, head h) block, 512 threads (8 waves), 2 blocks/CU.
//   phase 1: scores = 0.6*P_j + 0.4*sum_f a_f*|gs_jf + gt_if|  (Q_i term is
//            softmax-invariant and dropped). One j per thread, 8 i's.
//            i-tile 8 halves Gs_t L2 traffic vs i-tile 4 (each h-slice now
//            read by 64 blocks instead of 128).
//   phase 2: softmax, one wave per row; DIRECT scatter to out_att[i][j][h] —
//            the 8 h-blocks sharing a line are 64 apart in linear bid ->
//            64%8==0 -> same XCD -> writes combine in that XCD's L2 (this is
//            why round-0's scatter was never amplified; the pack-kernel
//            detour of round 1 only added traffic).
//   phase 3: head_output = att @ Gt; waves split j; uniform ds_read_b128
//            broadcasts of att rows; Gt rows reused across all 8 i's.
// ---------------------------------------------------------------------------
__global__ __launch_bounds__(512) void gat_attn(
    const float* __restrict__ Gs_t,      // [512 (h*64+f)][512 j]
    const float* __restrict__ Gt,        // [512 n][512 (h*64+f)]
    const float* __restrict__ attn_w,    // [64]
    const int*   __restrict__ adj,       // [512][512]
    float* __restrict__ out_feat,        // [512][512]
    float* __restrict__ out_att)         // [512][512][8]
{
    __shared__ float s_sc[8][512];
    __shared__ float s_red[8][8][64];

    const int tid = threadIdx.x;
    const int i0  = blockIdx.x * 8;
    const int h   = blockIdx.y;

    // ---- phase 1: scores (one j per thread, 8 i's) ----
    {
        const int j = tid;
        float acc[8];
        #pragma unroll
        for (int i = 0; i < 8; ++i) acc[i] = 0.f;
        float p = 0.f;                              // sum_f a_f * gs_jf
        const float* gsp = Gs_t + (size_t)h * NF * NN + j;
        const float* gtp = Gt + (size_t)i0 * IND + h * NF;
        #pragma unroll 4
        for (int f = 0; f < NF; ++f) {
            float w = attn_w[f];                    // uniform -> s_load
            float g = gsp[(size_t)f * NN];          // coalesced 256B/wave
            p = fmaf(w, g, p);
            #pragma unroll
            for (int i = 0; i < 8; ++i) {
                float t = g + gtp[(size_t)i * IND + f];  // uniform -> s_load
                acc[i] = fmaf(w, fabsf(t), acc[i]);
            }
        }
        const float px = 0.6f * p;
        #pragma unroll
        for (int i = 0; i < 8; ++i) {
            int ad = adj[(size_t)(i0 + i) * NN + j];
            s_sc[i][j] = ad ? fmaf(0.4f, acc[i], px) : -INFINITY;
        }
    }
    __syncthreads();

    // ---- phase 2: softmax (one wave per row) + direct attention scatter ----
    {
        const int w = tid >> 6, lane = tid & 63;
        float m = -INFINITY;
        #pragma unroll
        for (int r = 0; r < 8; ++r) m = fmaxf(m, s_sc[w][lane + r * 64]);
        #pragma unroll
        for (int off = 32; off >= 1; off >>= 1) m = fmaxf(m, __shfl_xor(m, off, 64));
        float e[8];
        float sum = 0.f;
        #pragma unroll
        for (int r = 0; r < 8; ++r) {
            float ev = __expf(s_sc[w][lane + r * 64] - m);
            e[r] = ev;
            sum += ev;
        }
        #pragma unroll
        for (int off = 32; off >= 1; off >>= 1) sum += __shfl_xor(sum, off, 64);
        float inv = 1.f / sum;
        const int i = i0 + w;
        #pragma unroll
        for (int r = 0; r < 8; ++r) {
            int j = lane + r * 64;
            float a = e[r] * inv;
            s_sc[w][j] = a;
            out_att[((size_t)i * NN + j) * NH + h] = a;
        }
    }
    __syncthreads();

    // ---- phase 3: head_output = att @ Gt (waves split j 64-wide) ----
    {
        const int w = tid >> 6, lane = tid & 63;
        const int jb = w * 64;
        float o[8];
        #pragma unroll
        for (int i = 0; i < 8; ++i) o[i] = 0.f;
        const float* gtc = Gt + h * NF + lane;
        #pragma unroll 2
        for (int s = 0; s < 16; ++s) {
            const int j = jb + 4 * s;
            float4 b[8];
            #pragma unroll
            for (int i = 0; i < 8; ++i)
                b[i] = *reinterpret_cast<const float4*>(&s_sc[i][j]);
            float gv;
            gv = gtc[(size_t)(j + 0) * IND];
            #pragma unroll
            for (int i = 0; i < 8; ++i) o[i] = fmaf(b[i].x, gv, o[i]);
            gv = gtc[(size_t)(j + 1) * IND];
            #pragma unroll
            for (int i = 0; i < 8; ++i) o[i] = fmaf(b[i].y, gv, o[i]);
            gv = gtc[(size_t)(j + 2) * IND];
            #pragma unroll
            for (int i = 0; i < 8; ++i) o[i] = fmaf(b[i].z, gv, o[i]);
            gv = gtc[(size_t)(j + 3) * IND];
            #pragma unroll
            for (int i = 0; i < 8; ++i) o[i] = fmaf(b[i].w, gv, o[i]);
        }
        #pragma unroll
        for (int i = 0; i < 8; ++i) s_red[w][i][lane] = o[i];
    }
    __syncthreads();
    {
        const int ii = tid >> 6, f = tid & 63;
        float s = 0.f;
        #pragma unroll
        for (int w = 0; w < 8; ++w) s += s_red[w][ii][f];
        out_feat[(size_t)(i0 + ii) * (NH * NF) + h * NF + f] = s;
    }
}

extern "C" void kernel_launch(void* const* d_in, const int* in_sizes, int n_in,
                              void* d_out, int out_size, void* d_ws, size_t ws_size,
                              hipStream_t stream) {
    const float* X   = (const float*)d_in[0];   // h [1,512,512]
    const float* Ws  = (const float*)d_in[1];   // W_source [512,512]
    const float* Wtg = (const float*)d_in[2];   // W_target [512,512]
    const float* aw  = (const float*)d_in[3];   // attn_w [64]
    const int*   adj = (const int*)d_in[4];     // adjacency [512,512,1]

    float* Gs_t = (float*)d_ws;                 // [512 o][512 n]
    float* Gt   = Gs_t + (size_t)NN * IND;      // [512 n][512 o]

    float* out_feat = (float*)d_out;                    // [512,512]
    float* out_att  = out_feat + (size_t)NN * NH * NF;  // [512,512,8]

    // K1: z=0: Gs_t = Ws . X^T ; z=1: Gt = X . Wt^T   (transpose fused via LDS)
    hipLaunchKernelGGL(gemm_nt, dim3(4, 64, 2), dim3(256), 0, stream,
                       Ws, X, Gs_t, X, Wtg, Gt);
    hipLaunchKernelGGL(gat_attn, dim3(NN / 8, NH), dim3(512), 0, stream,
                       Gs_t, Gt, aw, adj, out_feat, out_att);
}

// Round 3
// 103.363 us; speedup vs baseline: 1.0655x; 1.0370x over previous
//
#include <hip/hip_runtime.h>

#define NN 512          // nodes
#define IND 512         // in features
#define NH 8            // heads
#define NF 64           // hidden per head

// ---------------------------------------------------------------------------
// K1: fused NT GEMM (no pre-transpose): C[r][c] = sum_k A[r][k] * B[c][k]
//   z=0: A=Ws, B=X  -> C = Gs_t [o][n]
//   z=1: A=X,  B=Wt -> C = Gt   [n][o]
// Block: 16 r x 128 c, 512 thr = 8 waves = 4 row-groups x 2 k-halves
// (split-K in block). BR=16 halves B-panel L2 traffic vs BR=8 (traffic
// = 1MB * 512/BR): per-chunk feed 32 B/cyc/CU vs ~56 ceiling -> compute-bound.
// LDS double-buffered, ONE barrier per chunk; next chunk's global loads are
// issued before the barrier so L2/HBM latency hides under the 1024-cyc
// compute of the current chunk.
// Grid: (4, 32, 2) = 256 blocks = 1/CU.
// ---------------------------------------------------------------------------
__global__ __launch_bounds__(512) void gemm_nt(
    const float* __restrict__ Aa, const float* __restrict__ Ba, float* __restrict__ Ca,
    const float* __restrict__ Ab, const float* __restrict__ Bb, float* __restrict__ Cb)
{
    const float* A = blockIdx.z ? Ab : Aa;
    const float* B = blockIdx.z ? Bb : Ba;
    float*       C = blockIdx.z ? Cb : Ca;

    // pitch 132: write lanes are c-contiguous at fixed k -> 2-way (free);
    // float2 reads at c=2*lane -> <=4 words/bank, overlapped under 16cyc/k VALU.
    __shared__ __align__(16) float Vs[2][2][32][132];   // [dbuf][kh][k][c]
    __shared__ float2 sp[4][4][64];

    const int tid  = threadIdx.x;
    const int wv   = __builtin_amdgcn_readfirstlane(tid >> 6);
    const int lane = tid & 63;
    const int rg = wv & 3, kh = wv >> 2;
    const int r0 = blockIdx.y * 16 + rg * 4;
    const int c0 = blockIdx.x * 128;

    const float* Sp = A + (size_t)r0 * IND + kh * 256;

    // staging: 256 threads per k-half stage 128 c x 32 k per chunk;
    // 2 threads per column, 16 k (4 x float4 = 64B contiguous) each.
    const int ts = tid & 255;
    const int sc = ts & 127;
    const int kq = ts >> 7;
    const float* Brow = B + (size_t)(c0 + sc) * IND + kh * 256 + kq * 16;

    float2 a0 = {0.f,0.f}, a1 = {0.f,0.f}, a2 = {0.f,0.f}, a3 = {0.f,0.f};

    // ---- prologue: stage chunk 0 into buf 0
    float4 f[4];
    {
        const float4* bp = reinterpret_cast<const float4*>(Brow);
        #pragma unroll
        for (int i = 0; i < 4; ++i) f[i] = bp[i];
        #pragma unroll
        for (int i = 0; i < 4; ++i) {
            Vs[0][kh][kq * 16 + i * 4 + 0][sc] = f[i].x;
            Vs[0][kh][kq * 16 + i * 4 + 1][sc] = f[i].y;
            Vs[0][kh][kq * 16 + i * 4 + 2][sc] = f[i].z;
            Vs[0][kh][kq * 16 + i * 4 + 3][sc] = f[i].w;
        }
    }

    for (int ch = 0; ch < 8; ++ch) {
        // ---- issue next chunk's global loads (latency hides under compute)
        if (ch < 7) {
            const float4* bp = reinterpret_cast<const float4*>(Brow + (ch + 1) * 32);
            #pragma unroll
            for (int i = 0; i < 4; ++i) f[i] = bp[i];
        }
        __syncthreads();              // buf[ch&1] fully written; buf[(ch+1)&1] fully drained
        const float* Spc = Sp + ch * 32;
        const float (*V)[132] = Vs[ch & 1][kh];
        #pragma unroll 8
        for (int kk = 0; kk < 32; ++kk) {
            float2 v = *reinterpret_cast<const float2*>(&V[kk][lane * 2]);
            float s0 = Spc[kk];
            float s1 = Spc[IND + kk];
            float s2 = Spc[2 * IND + kk];
            float s3 = Spc[3 * IND + kk];
            a0.x = fmaf(s0, v.x, a0.x); a0.y = fmaf(s0, v.y, a0.y);
            a1.x = fmaf(s1, v.x, a1.x); a1.y = fmaf(s1, v.y, a1.y);
            a2.x = fmaf(s2, v.x, a2.x); a2.y = fmaf(s2, v.y, a2.y);
            a3.x = fmaf(s3, v.x, a3.x); a3.y = fmaf(s3, v.y, a3.y);
        }
        // ---- write next chunk (other buffer; safe: all waves passed the
        //      barrier above, hence finished reading it in iter ch-1)
        if (ch < 7) {
            #pragma unroll
            for (int i = 0; i < 4; ++i) {
                Vs[(ch + 1) & 1][kh][kq * 16 + i * 4 + 0][sc] = f[i].x;
                Vs[(ch + 1) & 1][kh][kq * 16 + i * 4 + 1][sc] = f[i].y;
                Vs[(ch + 1) & 1][kh][kq * 16 + i * 4 + 2][sc] = f[i].z;
                Vs[(ch + 1) & 1][kh][kq * 16 + i * 4 + 3][sc] = f[i].w;
            }
        }
    }

    // ---- split-K reduce + store (kh=1 exchanges via LDS, kh=0 writes C)
    if (kh) {
        sp[rg][0][lane] = a0; sp[rg][1][lane] = a1;
        sp[rg][2][lane] = a2; sp[rg][3][lane] = a3;
    }
    __syncthreads();
    if (!kh) {
        float2 p;
        const int cc = c0 + lane * 2;
        p = sp[rg][0][lane]; a0.x += p.x; a0.y += p.y;
        p = sp[rg][1][lane]; a1.x += p.x; a1.y += p.y;
        p = sp[rg][2][lane]; a2.x += p.x; a2.y += p.y;
        p = sp[rg][3][lane]; a3.x += p.x; a3.y += p.y;
        *reinterpret_cast<float2*>(C + (size_t)(r0 + 0) * NN + cc) = a0;
        *reinterpret_cast<float2*>(C + (size_t)(r0 + 1) * NN + cc) = a1;
        *reinterpret_cast<float2*>(C + (size_t)(r0 + 2) * NN + cc) = a2;
        *reinterpret_cast<float2*>(C + (size_t)(r0 + 3) * NN + cc) = a3;
    }
}

// ---------------------------------------------------------------------------
// K2: per (i-tile of 8, head h) block, 512 threads (8 waves), 2 blocks/CU.
//   phase 1: scores = 0.6*P_j + 0.4*sum_f a_f*|gs_jf + gt_if|  (Q_i term is
//            softmax-invariant and dropped). One j per thread, 8 i's;
//            2 VALU/element (v_add + v_fma with abs modifier) = floor.
//   phase 2: softmax, one wave per row; direct scatter to out_att[i][j][h]
//            (the 8 h-blocks sharing a line are 64 apart in linear bid ->
//            same XCD -> partial-line writes combine in that XCD's L2).
//   phase 3: head_output = att @ Gt; waves split j; uniform ds_read_b128
//            broadcasts of att rows (broadcast = conflict-free).
// ---------------------------------------------------------------------------
__global__ __launch_bounds__(512) void gat_attn(
    const float* __restrict__ Gs_t,      // [512 (h*64+f)][512 j]
    const float* __restrict__ Gt,        // [512 n][512 (h*64+f)]
    const float* __restrict__ attn_w,    // [64]
    const int*   __restrict__ adj,       // [512][512]
    float* __restrict__ out_feat,        // [512][512]
    float* __restrict__ out_att)         // [512][512][8]
{
    __shared__ float s_sc[8][512];
    __shared__ float s_red[8][8][64];

    const int tid = threadIdx.x;
    const int i0  = blockIdx.x * 8;
    const int h   = blockIdx.y;

    // ---- phase 1: scores (one j per thread, 8 i's) ----
    {
        const int j = tid;
        float acc[8];
        #pragma unroll
        for (int i = 0; i < 8; ++i) acc[i] = 0.f;
        float p = 0.f;                              // sum_f a_f * gs_jf
        const float* gsp = Gs_t + (size_t)h * NF * NN + j;
        const float* gtp = Gt + (size_t)i0 * IND + h * NF;
        #pragma unroll 4
        for (int f = 0; f < NF; ++f) {
            float w = attn_w[f];                    // uniform -> s_load
            float g = gsp[(size_t)f * NN];          // coalesced 256B/wave
            p = fmaf(w, g, p);
            #pragma unroll
            for (int i = 0; i < 8; ++i) {
                float t = g + gtp[(size_t)i * IND + f];  // uniform -> s_load
                acc[i] = fmaf(w, fabsf(t), acc[i]);
            }
        }
        const float px = 0.6f * p;
        #pragma unroll
        for (int i = 0; i < 8; ++i) {
            int ad = adj[(size_t)(i0 + i) * NN + j];
            s_sc[i][j] = ad ? fmaf(0.4f, acc[i], px) : -INFINITY;
        }
    }
    __syncthreads();

    // ---- phase 2: softmax (one wave per row) + direct attention scatter ----
    {
        const int w = tid >> 6, lane = tid & 63;
        float m = -INFINITY;
        #pragma unroll
        for (int r = 0; r < 8; ++r) m = fmaxf(m, s_sc[w][lane + r * 64]);
        #pragma unroll
        for (int off = 32; off >= 1; off >>= 1) m = fmaxf(m, __shfl_xor(m, off, 64));
        float e[8];
        float sum = 0.f;
        #pragma unroll
        for (int r = 0; r < 8; ++r) {
            float ev = __expf(s_sc[w][lane + r * 64] - m);
            e[r] = ev;
            sum += ev;
        }
        #pragma unroll
        for (int off = 32; off >= 1; off >>= 1) sum += __shfl_xor(sum, off, 64);
        float inv = 1.f / sum;
        const int i = i0 + w;
        #pragma unroll
        for (int r = 0; r < 8; ++r) {
            int j = lane + r * 64;
            float a = e[r] * inv;
            s_sc[w][j] = a;
            out_att[((size_t)i * NN + j) * NH + h] = a;
        }
    }
    __syncthreads();

    // ---- phase 3: head_output = att @ Gt (waves split j 64-wide) ----
    {
        const int w = tid >> 6, lane = tid & 63;
        const int jb = w * 64;
        float o[8];
        #pragma unroll
        for (int i = 0; i < 8; ++i) o[i] = 0.f;
        const float* gtc = Gt + h * NF + lane;
        #pragma unroll 2
        for (int s = 0; s < 16; ++s) {
            const int j = jb + 4 * s;
            float4 b[8];
            #pragma unroll
            for (int i = 0; i < 8; ++i)
                b[i] = *reinterpret_cast<const float4*>(&s_sc[i][j]);
            float gv;
            gv = gtc[(size_t)(j + 0) * IND];
            #pragma unroll
            for (int i = 0; i < 8; ++i) o[i] = fmaf(b[i].x, gv, o[i]);
            gv = gtc[(size_t)(j + 1) * IND];
            #pragma unroll
            for (int i = 0; i < 8; ++i) o[i] = fmaf(b[i].y, gv, o[i]);
            gv = gtc[(size_t)(j + 2) * IND];
            #pragma unroll
            for (int i = 0; i < 8; ++i) o[i] = fmaf(b[i].z, gv, o[i]);
            gv = gtc[(size_t)(j + 3) * IND];
            #pragma unroll
            for (int i = 0; i < 8; ++i) o[i] = fmaf(b[i].w, gv, o[i]);
        }
        #pragma unroll
        for (int i = 0; i < 8; ++i) s_red[w][i][lane] = o[i];
    }
    __syncthreads();
    {
        const int ii = tid >> 6, f = tid & 63;
        float s = 0.f;
        #pragma unroll
        for (int w = 0; w < 8; ++w) s += s_red[w][ii][f];
        out_feat[(size_t)(i0 + ii) * (NH * NF) + h * NF + f] = s;
    }
}

extern "C" void kernel_launch(void* const* d_in, const int* in_sizes, int n_in,
                              void* d_out, int out_size, void* d_ws, size_t ws_size,
                              hipStream_t stream) {
    const float* X   = (const float*)d_in[0];   // h [1,512,512]
    const float* Ws  = (const float*)d_in[1];   // W_source [512,512]
    const float* Wtg = (const float*)d_in[2];   // W_target [512,512]
    const float* aw  = (const float*)d_in[3];   // attn_w [64]
    const int*   adj = (const int*)d_in[4];     // adjacency [512,512,1]

    float* Gs_t = (float*)d_ws;                 // [512 o][512 n]
    float* Gt   = Gs_t + (size_t)NN * IND;      // [512 n][512 o]

    float* out_feat = (float*)d_out;                    // [512,512]
    float* out_att  = out_feat + (size_t)NN * NH * NF;  // [512,512,8]

    // K1: z=0: Gs_t = Ws . X^T ; z=1: Gt = X . Wt^T   (transpose fused via LDS)
    hipLaunchKernelGGL(gemm_nt, dim3(4, 32, 2), dim3(512), 0, stream,
                       Ws, X, Gs_t, X, Wtg, Gt);
    hipLaunchKernelGGL(gat_attn, dim3(NN / 8, NH), dim3(512), 0, stream,
                       Gs_t, Gt, aw, adj, out_feat, out_att);
}